// Round 15
// baseline (570.207 us; speedup 1.0000x reference)
//
#include <hip/hip_runtime.h>
#include <hip/hip_bf16.h>
#include <math.h>

// Bahdanau attention + reservoir RNN cell.
//  K0: Ua_w f32 -> bf16 in MFMA B-fragment layout (L2-resident, read direct)
//  K1: q = h_prev@Wa^T + Wa_b + Ua_b
//  K2: PERSISTENT deep-pipeline: 256 blocks x 512 thr (8 waves), 1 block/CU,
//      __launch_bounds__(512,2) -> 256-reg budget (acc 64 AGPR + ~116 arch,
//      no spill). Block owns (b-half, 16 chunks). LDS = 2x64KB bf16 A-tile
//      double buffer. Per chunk: ISSUE half1 -> 8 clusters (B-frag dbuf
//      prefetch, chunk-invariant rotation) -> WR half1 + ISSUE half2 ->
//      8 clusters -> WR half2 -> epilogue/softmax/context -> swap (3 barriers).
//      HBM staging hides under 8 clusters; B-L2 hides under previous cluster.
//  K3: exact combine of 32 partials -> context
//  K4: RNN cell (grid split over o for full-chip coverage)

typedef __attribute__((ext_vector_type(8))) short short8;
typedef __attribute__((ext_vector_type(8))) unsigned short ushort8;
typedef __attribute__((ext_vector_type(4))) float f32x4;

#define S_LEN 2048
#define BDIM 128
#define HDIM 512
#define EDIM 512
#define BM 64
#define NCHUNK (S_LEN / BM)  // 32

__device__ __forceinline__ unsigned short f2bf(float f) {
  unsigned int u = __float_as_uint(f);
  u += 0x7fffu + ((u >> 16) & 1u);  // RNE
  return (unsigned short)(u >> 16);
}

__device__ __forceinline__ float bf2f(unsigned short u) {
  return __uint_as_float(((unsigned int)u) << 16);
}

__device__ __forceinline__ float fast_tanh(float x) {
  float e = __expf(2.0f * x);
  return 1.0f - 2.0f / (e + 1.0f);
}

// Ua[512][512] f32 -> bf16 fragment layout:
// tile (ct,kt): col = ct*16 + (l&15), k = kt*32 + (l>>4)*8 + e
// at dst[((ct*16+kt)*64 + l)*8 + e]
__global__ __launch_bounds__(256) void k_cvt_b(const float* __restrict__ src,
                                               unsigned short* __restrict__ dst) {
  int tid = blockIdx.x * 256 + threadIdx.x;  // 0..32767
  int ct = tid >> 10;
  int kt = (tid >> 6) & 15;
  int l = tid & 63;
  int col = ct * 16 + (l & 15);
  int k = kt * 32 + (l >> 4) * 8;
  const float4* s = (const float4*)(src + (size_t)col * HDIM + k);
  float4 v0 = s[0], v1 = s[1];
  ushort8 p;
  p[0] = f2bf(v0.x); p[1] = f2bf(v0.y); p[2] = f2bf(v0.z); p[3] = f2bf(v0.w);
  p[4] = f2bf(v1.x); p[5] = f2bf(v1.y); p[6] = f2bf(v1.z); p[7] = f2bf(v1.w);
  *(ushort8*)(dst + (size_t)tid * 8) = p;
}

__global__ __launch_bounds__(256) void k_q(const float* __restrict__ hp,
                                           const float* __restrict__ Wa,
                                           const float* __restrict__ Wab,
                                           const float* __restrict__ Uab,
                                           float* __restrict__ q) {
  int b = blockIdx.x, oh = blockIdx.y;
  int o = oh * 256 + threadIdx.x;
  __shared__ float hs[HDIM];
  hs[threadIdx.x] = hp[b * HDIM + threadIdx.x];
  hs[threadIdx.x + 256] = hp[b * HDIM + threadIdx.x + 256];
  __syncthreads();
  const float4* wr = (const float4*)(Wa + (size_t)o * HDIM);
  float acc = 0.f;
#pragma unroll 8
  for (int i = 0; i < HDIM / 4; ++i) {
    float4 v = wr[i];
    acc += v.x * hs[i * 4 + 0] + v.y * hs[i * 4 + 1] + v.z * hs[i * 4 + 2] + v.w * hs[i * 4 + 3];
  }
  q[b * HDIM + o] = acc + Wab[o] + Uab[o];
}

__global__ __launch_bounds__(512, 2) void k_scores_ctx(
    const float* __restrict__ xref, const unsigned short* __restrict__ uab,
    const float* __restrict__ q, const float* __restrict__ va,
    float* __restrict__ mArr, float* __restrict__ lArr, float* __restrict__ cpart) {
  int p = blockIdx.x;            // 0..255
  int b = p >> 1;
  int chunk0 = (p & 1) * 16;     // this block's 16 chunks
  int tid = threadIdx.x;
  int l = tid & 63;
  int w = tid >> 6;              // 0..7, wave owns 64 rows x 64 cols
  int c = l & 15, g4 = l >> 4;

  // two bf16 tiles; logical byte (row,kb) at buf + row*1024 + (kb ^ ((row&7)<<4))
  __shared__ __align__(16) unsigned short As[2][BM * HDIM];  // 2 x 64 KB
  __shared__ float sc[BM];
  __shared__ float pl[BM];
  char* lds0 = (char*)&As[0][0];

  f32x4 acc[4][4];
#pragma unroll
  for (int m = 0; m < 4; ++m)
#pragma unroll
    for (int n = 0; n < 4; ++n) acc[m][n] = f32x4{0.f, 0.f, 0.f, 0.f};

  // staging geometry (R14): thread -> row = tid>>3, 8 f32 per p-chunk at
  // kb = (tid&7)*16 + p*128; slot-bijective per 8-lane group -> conflict-free
  int srow = tid >> 3, skq = tid & 7;
  int wboff = srow * 1024 + ((skq * 16) ^ ((srow & 7) << 4));
  const float* xbase = xref + ((size_t)b * S_LEN + (size_t)chunk0 * BM + srow) * HDIM + skq * 8;

  float4 a0, a1, a2, a3, a4, a5, a6, a7;
  short8 bA[4], bB[4];

#define LD2(va, vb, src, pp_)                                                  \
  {                                                                            \
    va = *(const float4*)((src) + (pp_) * 64);                                 \
    vb = *(const float4*)((src) + (pp_) * 64 + 4);                             \
  }

#define WR1(va, vb, nbuf, pp_)                                                 \
  {                                                                            \
    union { __hip_bfloat162 h[4]; ushort8 s; } u_;                             \
    u_.h[0] = __float22bfloat162_rn(make_float2(va.x, va.y));                  \
    u_.h[1] = __float22bfloat162_rn(make_float2(va.z, va.w));                  \
    u_.h[2] = __float22bfloat162_rn(make_float2(vb.x, vb.y));                  \
    u_.h[3] = __float22bfloat162_rn(make_float2(vb.z, vb.w));                  \
    *(ushort8*)((nbuf) + wboff + (pp_) * 128) = u_.s;                          \
  }

#define LOADB(dst, kt)                                                         \
  {                                                                            \
    _Pragma("unroll")                                                          \
    for (int n = 0; n < 4; ++n)                                                \
      dst[n] = *(const short8*)(uab +                                          \
               (((size_t)((w * 4 + n) * 16 + (kt)) * 64 + l) * 8));            \
  }

  // cluster: prefetch bpre(ktn) from L2, read A-frags(kt) from cbuf, 16 MFMA on buse
#define CLUSTERP(buse, bpre, cbuf, kt, ktn)                                    \
  {                                                                            \
    LOADB(bpre, ktn)                                                           \
    short8 afr_[4];                                                            \
    _Pragma("unroll")                                                          \
    for (int m = 0; m < 4; ++m) {                                              \
      int row = m * 16 + (l & 15);                                             \
      int kb = ((kt) * 64 + (l >> 4) * 16) ^ ((row & 7) << 4);                 \
      afr_[m] = *(const short8*)((cbuf) + row * 1024 + kb);                    \
    }                                                                          \
    __builtin_amdgcn_s_setprio(1);                                             \
    _Pragma("unroll")                                                          \
    for (int m = 0; m < 4; ++m)                                                \
      _Pragma("unroll")                                                        \
      for (int n = 0; n < 4; ++n)                                              \
        acc[m][n] = __builtin_amdgcn_mfma_f32_16x16x32_bf16(afr_[m], buse[n],  \
                                                            acc[m][n], 0, 0, 0); \
    __builtin_amdgcn_s_setprio(0);                                             \
  }

  // per-block q/Va (chunk-invariant)
  float qf[4], vf[4];
#pragma unroll
  for (int n = 0; n < 4; ++n) {
    int o = w * 64 + n * 16 + c;
    qf[n] = q[b * HDIM + o];
    vf[n] = va[o];
  }

  // prologue: stage tile chunk0 into buf0; preload bA(kt=0)
  LOADB(bA, 0)
  LD2(a0, a1, xbase, 0) LD2(a2, a3, xbase, 1) LD2(a4, a5, xbase, 2) LD2(a6, a7, xbase, 3)
  WR1(a0, a1, lds0, 0) WR1(a2, a3, lds0, 1) WR1(a4, a5, lds0, 2) WR1(a6, a7, lds0, 3)
  LD2(a0, a1, xbase, 4) LD2(a2, a3, xbase, 5) LD2(a4, a5, xbase, 6) LD2(a6, a7, xbase, 7)
  WR1(a0, a1, lds0, 4) WR1(a2, a3, lds0, 5) WR1(a4, a5, lds0, 6) WR1(a6, a7, lds0, 7)
  if (tid < BM) sc[tid] = 0.f;
  __syncthreads();

  int cur = 0;
#pragma unroll 1
  for (int i = 0; i < 16; ++i) {
    char* cbuf = lds0 + cur * 65536;
    char* nbuf = lds0 + (cur ^ 1) * 65536;
    const float* xnext = xbase + (size_t)(i + 1) * BM * HDIM;
    bool notlast = (i < 15);

    // issue half 1 of next tile (HBM latency hides under 8 clusters)
    if (notlast) { LD2(a0, a1, xnext, 0) LD2(a2, a3, xnext, 1) LD2(a4, a5, xnext, 2) LD2(a6, a7, xnext, 3) }

    CLUSTERP(bA, bB, cbuf, 0, 1)  CLUSTERP(bB, bA, cbuf, 1, 2)
    CLUSTERP(bA, bB, cbuf, 2, 3)  CLUSTERP(bB, bA, cbuf, 3, 4)
    CLUSTERP(bA, bB, cbuf, 4, 5)  CLUSTERP(bB, bA, cbuf, 5, 6)
    CLUSTERP(bA, bB, cbuf, 6, 7)  CLUSTERP(bB, bA, cbuf, 7, 8)

    if (notlast) {
      WR1(a0, a1, nbuf, 0) WR1(a2, a3, nbuf, 1) WR1(a4, a5, nbuf, 2) WR1(a6, a7, nbuf, 3)
      LD2(a0, a1, xnext, 4) LD2(a2, a3, xnext, 5) LD2(a4, a5, xnext, 6) LD2(a6, a7, xnext, 7)
    }

    CLUSTERP(bA, bB, cbuf, 8, 9)   CLUSTERP(bB, bA, cbuf, 9, 10)
    CLUSTERP(bA, bB, cbuf, 10, 11) CLUSTERP(bB, bA, cbuf, 11, 12)
    CLUSTERP(bA, bB, cbuf, 12, 13) CLUSTERP(bB, bA, cbuf, 13, 14)
    CLUSTERP(bA, bB, cbuf, 14, 15) CLUSTERP(bB, bA, cbuf, 15, 0)  // wraps: bA(kt0) ready for next chunk

    if (notlast) { WR1(a0, a1, nbuf, 4) WR1(a2, a3, nbuf, 5) WR1(a4, a5, nbuf, 6) WR1(a6, a7, nbuf, 7) }

    // scores[row] = sum_o tanh(acc + q[o]) * Va[o]
#pragma unroll
    for (int m = 0; m < 4; ++m) {
#pragma unroll
      for (int r = 0; r < 4; ++r) {
        float sum = 0.f;
#pragma unroll
        for (int n = 0; n < 4; ++n) sum += fast_tanh(acc[m][n][r] + qf[n]) * vf[n];
        sum += __shfl_xor(sum, 1);
        sum += __shfl_xor(sum, 2);
        sum += __shfl_xor(sum, 4);
        sum += __shfl_xor(sum, 8);
        if (c == 0) atomicAdd(&sc[m * 16 + g4 * 4 + r], sum);
      }
    }
#pragma unroll
    for (int m = 0; m < 4; ++m)
#pragma unroll
      for (int n = 0; n < 4; ++n) acc[m][n] = f32x4{0.f, 0.f, 0.f, 0.f};
    __syncthreads();  // sc complete (and all staging writes done)

    // softmax over the 64 local rows
    float M = sc[l];
#pragma unroll
    for (int off = 32; off >= 1; off >>= 1) M = fmaxf(M, __shfl_xor(M, off));
    float pp = __expf(sc[l] - M);
    float lsum = pp;
#pragma unroll
    for (int off = 32; off >= 1; off >>= 1) lsum += __shfl_xor(lsum, off);
    if (tid < BM) pl[tid] = pp;
    if (tid == 0) {
      mArr[b * NCHUNK + chunk0 + i] = M;
      lArr[b * NCHUNK + chunk0 + i] = lsum;
    }
    __syncthreads();  // pl ready; sc reads done
    if (tid < BM) sc[tid] = 0.f;

    // partial context from cbuf: thread = one of 512 cols
    {
      int h2 = tid * 2;
      float cacc = 0.f;
#pragma unroll 8
      for (int r = 0; r < BM; ++r) {
        int byte = r * 1024 + (h2 ^ ((r & 7) << 4));
        cacc += pl[r] * bf2f(*(const unsigned short*)(cbuf + byte));
      }
      cpart[((size_t)b * NCHUNK + chunk0 + i) * HDIM + tid] = cacc;
    }
    __syncthreads();  // cbuf consumed; next iter may overwrite it
    cur ^= 1;
  }
#undef LD2
#undef WR1
#undef LOADB
#undef CLUSTERP
}

__global__ __launch_bounds__(512) void k_combine(const float* __restrict__ mArr,
                                                 const float* __restrict__ lArr,
                                                 const float* __restrict__ cpart,
                                                 float* __restrict__ ctx,
                                                 float* __restrict__ out_ctx) {
  int b = blockIdx.x, t = threadIdx.x;
  __shared__ float wf[NCHUNK];
  __shared__ float dinv;
  if (t == 0) {
    float M = mArr[b * NCHUNK];
    for (int i = 1; i < NCHUNK; ++i) M = fmaxf(M, mArr[b * NCHUNK + i]);
    float den = 0.f;
    for (int i = 0; i < NCHUNK; ++i) {
      float f = __expf(mArr[b * NCHUNK + i] - M);
      wf[i] = f;
      den += f * lArr[b * NCHUNK + i];
    }
    dinv = 1.0f / den;
  }
  __syncthreads();
  float s = 0.f;
#pragma unroll
  for (int i = 0; i < NCHUNK; ++i) s += wf[i] * cpart[((size_t)b * NCHUNK + i) * HDIM + t];
  float c = s * dinv;
  ctx[b * HDIM + t] = c;
  out_ctx[b * HDIM + t] = c;
}

__global__ __launch_bounds__(256) void k_rnn(const float* __restrict__ xt,
                                             const float* __restrict__ ctx,
                                             const float* __restrict__ hp,
                                             const float* __restrict__ Wih,
                                             const float* __restrict__ Wihb,
                                             const float* __restrict__ Whh,
                                             const float* __restrict__ Whhb,
                                             float* __restrict__ hout) {
  int b = blockIdx.x, oh = blockIdx.y;
  int o = oh * 256 + threadIdx.x;
  __shared__ float xs[EDIM], cs[HDIM], hs[HDIM];
  xs[threadIdx.x] = xt[b * EDIM + threadIdx.x];
  xs[threadIdx.x + 256] = xt[b * EDIM + threadIdx.x + 256];
  cs[threadIdx.x] = ctx[b * HDIM + threadIdx.x];
  cs[threadIdx.x + 256] = ctx[b * HDIM + threadIdx.x + 256];
  hs[threadIdx.x] = hp[b * HDIM + threadIdx.x];
  hs[threadIdx.x + 256] = hp[b * HDIM + threadIdx.x + 256];
  __syncthreads();
  const float4* wi = (const float4*)(Wih + (size_t)o * (EDIM + HDIM));
  float acc = Wihb[o] + Whhb[o];
#pragma unroll 8
  for (int i = 0; i < EDIM / 4; ++i) {
    float4 v = wi[i];
    acc += v.x * xs[i * 4] + v.y * xs[i * 4 + 1] + v.z * xs[i * 4 + 2] + v.w * xs[i * 4 + 3];
  }
  const float4* wi2 = wi + EDIM / 4;
#pragma unroll 8
  for (int i = 0; i < HDIM / 4; ++i) {
    float4 v = wi2[i];
    acc += v.x * cs[i * 4] + v.y * cs[i * 4 + 1] + v.z * cs[i * 4 + 2] + v.w * cs[i * 4 + 3];
  }
  const float4* wh = (const float4*)(Whh + (size_t)o * HDIM);
#pragma unroll 8
  for (int i = 0; i < HDIM / 4; ++i) {
    float4 v = wh[i];
    acc += v.x * hs[i * 4] + v.y * hs[i * 4 + 1] + v.z * hs[i * 4 + 2] + v.w * hs[i * 4 + 3];
  }
  hout[b * HDIM + o] = tanhf(acc);
}

extern "C" void kernel_launch(void* const* d_in, const int* in_sizes, int n_in,
                              void* d_out, int out_size, void* d_ws, size_t ws_size,
                              hipStream_t stream) {
  const float* x_t    = (const float*)d_in[0];
  const float* x_ref  = (const float*)d_in[1];
  const float* h_prev = (const float*)d_in[2];
  const float* Wa_w   = (const float*)d_in[3];
  const float* Wa_b   = (const float*)d_in[4];
  const float* Ua_w   = (const float*)d_in[5];
  const float* Ua_b   = (const float*)d_in[6];
  const float* Va_w   = (const float*)d_in[7];
  // d_in[8] = Va_b: softmax-invariant, skipped.
  const float* Wih_w  = (const float*)d_in[9];
  const float* Wih_b  = (const float*)d_in[10];
  const float* Whh_w  = (const float*)d_in[11];
  const float* Whh_b  = (const float*)d_in[12];

  char* ws = (char*)d_ws;
  unsigned short* ua_fr = (unsigned short*)ws;   // 512 KB fragment-layout Ua
  float* q     = (float*)(ws + 524288);          // 256 KB
  float* mArr  = (float*)(ws + 786432);          // 16 KB
  float* lArr  = (float*)(ws + 802816);          // 16 KB
  float* cpart = (float*)(ws + 819200);          // 8 MB
  float* ctx   = (float*)(ws + 9207808);         // 256 KB

  float* h_out   = (float*)d_out;
  float* ctx_out = h_out + BDIM * HDIM;

  k_cvt_b<<<dim3(128), dim3(256), 0, stream>>>(Ua_w, ua_fr);
  k_q<<<dim3(BDIM, 2), dim3(256), 0, stream>>>(h_prev, Wa_w, Wa_b, Ua_b, q);
  k_scores_ctx<<<dim3(256), dim3(512), 0, stream>>>(x_ref, ua_fr, q, Va_w, mArr, lArr, cpart);
  k_combine<<<dim3(BDIM), dim3(512), 0, stream>>>(mArr, lArr, cpart, ctx, ctx_out);
  k_rnn<<<dim3(BDIM, 2), dim3(256), 0, stream>>>(x_t, ctx, h_prev, Wih_w, Wih_b, Whh_w, Whh_b, h_out);
}

// Round 16
// 293.036 us; speedup vs baseline: 1.9459x; 1.9459x over previous
//
#include <hip/hip_runtime.h>
#include <hip/hip_bf16.h>
#include <math.h>

// Bahdanau attention + reservoir RNN cell.  (R14 structure = session best.)
//  K0: Ua_w f32 -> bf16 in MFMA B-fragment layout (L2-resident, read direct)
//  K1: q = h_prev@Wa^T + Wa_b + Ua_b
//  K2: per (b, 64-row chunk): 512 thr / 8 waves, (512,4) -> 2 blocks/CU,
//      4 waves/SIMD. Wave = 64 rows x 64 cols, acc 4x4 = 64 AGPR (+~60 arch
//      <= 128: no spill). 16-MFMA clusters x 4 waves/SIMD cover the L2
//      latency window (the R7/R13 155-cy configs pinned MfmaUtil at 17%).
//      Staging: transient-reg f32->bf16 cvt, slot-bijective XOR'd ds_write
//      (conflict-free both sides). B-frags direct from L2 per cluster;
//      cluster-0's B prefetched pre-barrier (covers the L2 ramp).
//      CONSTRAINT WEB (measured R4-R15): held-staging regs + acc64 spills
//      at ANY launch_bounds; 1024-thr blocks pinned to 64 VGPR; dbuf LDS
//      kills 2-blocks/CU. This config is the feasible optimum.
//  K3: exact combine of 32 partials -> context
//  K4: RNN cell (grid split over o for full-chip coverage)

typedef __attribute__((ext_vector_type(8))) short short8;
typedef __attribute__((ext_vector_type(8))) unsigned short ushort8;
typedef __attribute__((ext_vector_type(4))) float f32x4;

#define S_LEN 2048
#define BDIM 128
#define HDIM 512
#define EDIM 512
#define BM 64
#define NCHUNK (S_LEN / BM)  // 32

__device__ __forceinline__ unsigned short f2bf(float f) {
  unsigned int u = __float_as_uint(f);
  u += 0x7fffu + ((u >> 16) & 1u);  // RNE
  return (unsigned short)(u >> 16);
}

__device__ __forceinline__ float bf2f(unsigned short u) {
  return __uint_as_float(((unsigned int)u) << 16);
}

__device__ __forceinline__ float fast_tanh(float x) {
  float e = __expf(2.0f * x);
  return 1.0f - 2.0f / (e + 1.0f);
}

// Ua[512][512] f32 -> bf16 fragment layout:
// tile (ct,kt): col = ct*16 + (l&15), k = kt*32 + (l>>4)*8 + e
// at dst[((ct*16+kt)*64 + l)*8 + e]
__global__ __launch_bounds__(256) void k_cvt_b(const float* __restrict__ src,
                                               unsigned short* __restrict__ dst) {
  int tid = blockIdx.x * 256 + threadIdx.x;  // 0..32767
  int ct = tid >> 10;
  int kt = (tid >> 6) & 15;
  int l = tid & 63;
  int col = ct * 16 + (l & 15);
  int k = kt * 32 + (l >> 4) * 8;
  const float4* s = (const float4*)(src + (size_t)col * HDIM + k);
  float4 v0 = s[0], v1 = s[1];
  ushort8 p;
  p[0] = f2bf(v0.x); p[1] = f2bf(v0.y); p[2] = f2bf(v0.z); p[3] = f2bf(v0.w);
  p[4] = f2bf(v1.x); p[5] = f2bf(v1.y); p[6] = f2bf(v1.z); p[7] = f2bf(v1.w);
  *(ushort8*)(dst + (size_t)tid * 8) = p;
}

__global__ __launch_bounds__(256) void k_q(const float* __restrict__ hp,
                                           const float* __restrict__ Wa,
                                           const float* __restrict__ Wab,
                                           const float* __restrict__ Uab,
                                           float* __restrict__ q) {
  int b = blockIdx.x, oh = blockIdx.y;
  int o = oh * 256 + threadIdx.x;
  __shared__ float hs[HDIM];
  hs[threadIdx.x] = hp[b * HDIM + threadIdx.x];
  hs[threadIdx.x + 256] = hp[b * HDIM + threadIdx.x + 256];
  __syncthreads();
  const float4* wr = (const float4*)(Wa + (size_t)o * HDIM);
  float acc = 0.f;
#pragma unroll 8
  for (int i = 0; i < HDIM / 4; ++i) {
    float4 v = wr[i];
    acc += v.x * hs[i * 4 + 0] + v.y * hs[i * 4 + 1] + v.z * hs[i * 4 + 2] + v.w * hs[i * 4 + 3];
  }
  q[b * HDIM + o] = acc + Wab[o] + Uab[o];
}

__global__ __launch_bounds__(512, 4) void k_scores_ctx(
    const float* __restrict__ xref, const unsigned short* __restrict__ uab,
    const float* __restrict__ q, const float* __restrict__ va,
    float* __restrict__ mArr, float* __restrict__ lArr, float* __restrict__ cpart) {
  int chunk = blockIdx.x;
  int b = blockIdx.y;
  int tid = threadIdx.x;
  int l = tid & 63;
  int w = tid >> 6;          // 0..7, wave owns 64 rows x 64 cols
  int c = l & 15, g4 = l >> 4;

  // bf16 tile; logical byte (row,kb) stored at row*1024 + (kb ^ ((row&7)<<4))
  __shared__ __align__(16) unsigned short As[BM * HDIM];  // 64 KB
  __shared__ float sc[BM];
  __shared__ float pl[BM];

  f32x4 acc[4][4];
#pragma unroll
  for (int m = 0; m < 4; ++m)
#pragma unroll
    for (int n = 0; n < 4; ++n) acc[m][n] = f32x4{0.f, 0.f, 0.f, 0.f};

  const float* xb = xref + ((size_t)b * S_LEN + (size_t)chunk * BM) * HDIM;

  // staging: thread -> row = tid>>3 (8 lanes/row); per p-chunk the thread
  // covers 8 f32 (16 bf16 B) at kb = (tid&7)*16 + p*128.
  // slot = ((tid&7)*16 ^ ((row&7)<<4)) is a bijection per 8-lane group.
  int srow = tid >> 3, skq = tid & 7;
  char* wb = (char*)&As[0] + srow * 1024 + ((skq * 16) ^ ((srow & 7) << 4));
  const float* sb = xb + (size_t)srow * HDIM + skq * 8;

  float4 a0, a1, a2, a3, a4, a5, a6, a7;
  short8 bpre[4];

#define LD2(va, vb, p)                                                         \
  {                                                                            \
    va = *(const float4*)(sb + (p) * 64);                                      \
    vb = *(const float4*)(sb + (p) * 64 + 4);                                  \
  }

#define WR1(va, vb, p)                                                         \
  {                                                                            \
    union { __hip_bfloat162 h[4]; ushort8 s; } u_;                             \
    u_.h[0] = __float22bfloat162_rn(make_float2(va.x, va.y));                  \
    u_.h[1] = __float22bfloat162_rn(make_float2(va.z, va.w));                  \
    u_.h[2] = __float22bfloat162_rn(make_float2(vb.x, vb.y));                  \
    u_.h[3] = __float22bfloat162_rn(make_float2(vb.z, vb.w));                  \
    *(ushort8*)(wb + (p) * 128) = u_.s;                                        \
  }

  // A-fragment reads for k-tile kt (shared by both cluster forms)
#define AFRAGS(kt)                                                             \
    short8 afr_[4];                                                            \
    _Pragma("unroll")                                                          \
    for (int m = 0; m < 4; ++m) {                                              \
      int row = m * 16 + (l & 15);                                             \
      int kb = ((kt) * 64 + (l >> 4) * 16) ^ ((row & 7) << 4);                 \
      afr_[m] = *(const short8*)((const char*)&As[0] + row * 1024 + kb);       \
    }

#define MFMA16(bsrc)                                                           \
    __builtin_amdgcn_s_setprio(1);                                             \
    _Pragma("unroll")                                                          \
    for (int m = 0; m < 4; ++m)                                                \
      _Pragma("unroll")                                                        \
      for (int n = 0; n < 4; ++n)                                              \
        acc[m][n] = __builtin_amdgcn_mfma_f32_16x16x32_bf16(afr_[m], bsrc[n],  \
                                                            acc[m][n], 0, 0, 0); \
    __builtin_amdgcn_s_setprio(0);

  // 16-MFMA cluster for k-tile kt, B loaded inline from L2
#define CLUSTER(kt)                                                            \
  {                                                                            \
    short8 bfr_[4];                                                            \
    _Pragma("unroll")                                                          \
    for (int n = 0; n < 4; ++n) {                                              \
      int ct = w * 4 + n;                                                      \
      bfr_[n] = *(const short8*)(uab + (((size_t)(ct * 16 + (kt)) * 64 + l) * 8)); \
    }                                                                          \
    AFRAGS(kt)                                                                 \
    MFMA16(bfr_)                                                               \
  }

  // cluster consuming the preloaded B set
#define CLUSTER_PRE(kt)                                                        \
  {                                                                            \
    AFRAGS(kt)                                                                 \
    MFMA16(bpre)                                                               \
  }

  // stage the full 64x512 tile: 2 load batches (32 regs), 2 latency waits
  LD2(a0, a1, 0) LD2(a2, a3, 1) LD2(a4, a5, 2) LD2(a6, a7, 3)
  WR1(a0, a1, 0) WR1(a2, a3, 1) WR1(a4, a5, 2) WR1(a6, a7, 3)
  LD2(a0, a1, 4) LD2(a2, a3, 5) LD2(a4, a5, 6) LD2(a6, a7, 7)
  WR1(a0, a1, 4) WR1(a2, a3, 5) WR1(a4, a5, 6) WR1(a6, a7, 7)
  if (tid < BM) sc[tid] = 0.f;
  // prefetch cluster-0 B fragments (LDS-independent; covers L2 ramp at barrier)
#pragma unroll
  for (int n = 0; n < 4; ++n)
    bpre[n] = *(const short8*)(uab + (((size_t)((w * 4 + n) * 16 + 0) * 64 + l) * 8));
  __syncthreads();

  CLUSTER_PRE(0)
  CLUSTER(1)  CLUSTER(2)  CLUSTER(3)
  CLUSTER(4)  CLUSTER(5)  CLUSTER(6)  CLUSTER(7)
  CLUSTER(8)  CLUSTER(9)  CLUSTER(10) CLUSTER(11)
  CLUSTER(12) CLUSTER(13)

  // q/Va loads hoisted under the last two clusters
  float qf[4], vf[4];
#pragma unroll
  for (int n = 0; n < 4; ++n) {
    int o = w * 64 + n * 16 + c;
    qf[n] = q[b * HDIM + o];
    vf[n] = va[o];
  }
  CLUSTER(14) CLUSTER(15)

  // scores[row] = sum_o tanh(acc + q[o]) * Va[o]
#pragma unroll
  for (int m = 0; m < 4; ++m) {
#pragma unroll
    for (int r = 0; r < 4; ++r) {
      float sum = 0.f;
#pragma unroll
      for (int n = 0; n < 4; ++n) sum += fast_tanh(acc[m][n][r] + qf[n]) * vf[n];
      sum += __shfl_xor(sum, 1);
      sum += __shfl_xor(sum, 2);
      sum += __shfl_xor(sum, 4);
      sum += __shfl_xor(sum, 8);
      if (c == 0) atomicAdd(&sc[m * 16 + g4 * 4 + r], sum);
    }
  }
  __syncthreads();

  // softmax over the 64 local rows (each wave computes identically)
  float M = sc[l];
#pragma unroll
  for (int off = 32; off >= 1; off >>= 1) M = fmaxf(M, __shfl_xor(M, off));
  float pp = __expf(sc[l] - M);
  float lsum = pp;
#pragma unroll
  for (int off = 32; off >= 1; off >>= 1) lsum += __shfl_xor(lsum, off);
  if (tid < BM) pl[tid] = pp;
  if (tid == 0) {
    mArr[b * NCHUNK + chunk] = M;
    lArr[b * NCHUNK + chunk] = lsum;
  }
  __syncthreads();

  // partial context from the bf16 LDS tile: thread = one of 512 cols
  {
    int h2 = tid * 2;  // logical kbyte of this col
    const char* base_ = (const char*)&As[0];
    float cacc = 0.f;
#pragma unroll 8
    for (int r = 0; r < BM; ++r) {
      int byte = r * 1024 + (h2 ^ ((r & 7) << 4));
      cacc += pl[r] * bf2f(*(const unsigned short*)(base_ + byte));
    }
    cpart[((size_t)b * NCHUNK + chunk) * HDIM + tid] = cacc;
  }
#undef LD2
#undef WR1
#undef AFRAGS
#undef MFMA16
#undef CLUSTER
#undef CLUSTER_PRE
}

__global__ __launch_bounds__(512) void k_combine(const float* __restrict__ mArr,
                                                 const float* __restrict__ lArr,
                                                 const float* __restrict__ cpart,
                                                 float* __restrict__ ctx,
                                                 float* __restrict__ out_ctx) {
  int b = blockIdx.x, t = threadIdx.x;
  __shared__ float wf[NCHUNK];
  __shared__ float dinv;
  if (t == 0) {
    float M = mArr[b * NCHUNK];
    for (int i = 1; i < NCHUNK; ++i) M = fmaxf(M, mArr[b * NCHUNK + i]);
    float den = 0.f;
    for (int i = 0; i < NCHUNK; ++i) {
      float f = __expf(mArr[b * NCHUNK + i] - M);
      wf[i] = f;
      den += f * lArr[b * NCHUNK + i];
    }
    dinv = 1.0f / den;
  }
  __syncthreads();
  float s = 0.f;
#pragma unroll
  for (int i = 0; i < NCHUNK; ++i) s += wf[i] * cpart[((size_t)b * NCHUNK + i) * HDIM + t];
  float c = s * dinv;
  ctx[b * HDIM + t] = c;
  out_ctx[b * HDIM + t] = c;
}

__global__ __launch_bounds__(256) void k_rnn(const float* __restrict__ xt,
                                             const float* __restrict__ ctx,
                                             const float* __restrict__ hp,
                                             const float* __restrict__ Wih,
                                             const float* __restrict__ Wihb,
                                             const float* __restrict__ Whh,
                                             const float* __restrict__ Whhb,
                                             float* __restrict__ hout) {
  int b = blockIdx.x, oh = blockIdx.y;
  int o = oh * 256 + threadIdx.x;
  __shared__ float xs[EDIM], cs[HDIM], hs[HDIM];
  xs[threadIdx.x] = xt[b * EDIM + threadIdx.x];
  xs[threadIdx.x + 256] = xt[b * EDIM + threadIdx.x + 256];
  cs[threadIdx.x] = ctx[b * HDIM + threadIdx.x];
  cs[threadIdx.x + 256] = ctx[b * HDIM + threadIdx.x + 256];
  hs[threadIdx.x] = hp[b * HDIM + threadIdx.x];
  hs[threadIdx.x + 256] = hp[b * HDIM + threadIdx.x + 256];
  __syncthreads();
  const float4* wi = (const float4*)(Wih + (size_t)o * (EDIM + HDIM));
  float acc = Wihb[o] + Whhb[o];
#pragma unroll 8
  for (int i = 0; i < EDIM / 4; ++i) {
    float4 v = wi[i];
    acc += v.x * xs[i * 4] + v.y * xs[i * 4 + 1] + v.z * xs[i * 4 + 2] + v.w * xs[i * 4 + 3];
  }
  const float4* wi2 = wi + EDIM / 4;
#pragma unroll 8
  for (int i = 0; i < HDIM / 4; ++i) {
    float4 v = wi2[i];
    acc += v.x * cs[i * 4] + v.y * cs[i * 4 + 1] + v.z * cs[i * 4 + 2] + v.w * cs[i * 4 + 3];
  }
  const float4* wh = (const float4*)(Whh + (size_t)o * HDIM);
#pragma unroll 8
  for (int i = 0; i < HDIM / 4; ++i) {
    float4 v = wh[i];
    acc += v.x * hs[i * 4] + v.y * hs[i * 4 + 1] + v.z * hs[i * 4 + 2] + v.w * hs[i * 4 + 3];
  }
  hout[b * HDIM + o] = tanhf(acc);
}

extern "C" void kernel_launch(void* const* d_in, const int* in_sizes, int n_in,
                              void* d_out, int out_size, void* d_ws, size_t ws_size,
                              hipStream_t stream) {
  const float* x_t    = (const float*)d_in[0];
  const float* x_ref  = (const float*)d_in[1];
  const float* h_prev = (const float*)d_in[2];
  const float* Wa_w   = (const float*)d_in[3];
  const float* Wa_b   = (const float*)d_in[4];
  const float* Ua_w   = (const float*)d_in[5];
  const float* Ua_b   = (const float*)d_in[6];
  const float* Va_w   = (const float*)d_in[7];
  // d_in[8] = Va_b: softmax-invariant, skipped.
  const float* Wih_w  = (const float*)d_in[9];
  const float* Wih_b  = (const float*)d_in[10];
  const float* Whh_w  = (const float*)d_in[11];
  const float* Whh_b  = (const float*)d_in[12];

  char* ws = (char*)d_ws;
  unsigned short* ua_fr = (unsigned short*)ws;   // 512 KB fragment-layout Ua
  float* q     = (float*)(ws + 524288);          // 256 KB
  float* mArr  = (float*)(ws + 786432);          // 16 KB
  float* lArr  = (float*)(ws + 802816);          // 16 KB
  float* cpart = (float*)(ws + 819200);          // 8 MB
  float* ctx   = (float*)(ws + 9207808);         // 256 KB

  float* h_out   = (float*)d_out;
  float* ctx_out = h_out + BDIM * HDIM;

  k_cvt_b<<<dim3(128), dim3(256), 0, stream>>>(Ua_w, ua_fr);
  k_q<<<dim3(BDIM, 2), dim3(256), 0, stream>>>(h_prev, Wa_w, Wa_b, Ua_b, q);
  k_scores_ctx<<<dim3(NCHUNK, BDIM), dim3(512), 0, stream>>>(x_ref, ua_fr, q, Va_w, mArr, lArr, cpart);
  k_combine<<<dim3(BDIM), dim3(512), 0, stream>>>(mArr, lArr, cpart, ctx, ctx_out);
  k_rnn<<<dim3(BDIM, 2), dim3(256), 0, stream>>>(x_t, ctx, h_prev, Wih_w, Wih_b, Whh_w, Whh_b, h_out);
}